// Round 3
// baseline (93.111 us; speedup 1.0000x reference)
//
#include <hip/hip_runtime.h>

// Problem constants (from reference): B=32, L=4096, D=128, N=5, V=128
constexpr int Bn = 32;
constexpr int Ln = 4096;
constexpr int Dn = 128;
constexpr int Vn = 128;
constexpr int N1 = 4;  // N - 1 context slots

typedef float vfloat4 __attribute__((ext_vector_type(4)));  // native vec for nontemporal builtins

// T layout (R8): [4 v-quarters][4 slots][128 tokens][32 v] fp32 = 256 KiB.
// Quarter-major so kernel B stages one contiguous 64 KiB slice per block into LDS.
// R7 post-mortem: v-EIGHTH slices made wave stores 64 B scattered chunks (half an
// L2 line) -> ~2x write cost, +8 us. Quarter slices give 128 B full-line chunks.
//
// Kernel A: T[q][k][t][vlo] = dot(emb[t], W[v, k*D:(k+1)*D]) (+ bias[v] for k==0),
// v = q*32 + vlo. grid: 4*128 = 512 blocks (one per (k,t)), block: 128 threads (v).
// NOTE (R4/R6 evidence): coalesced/transposed/shuffle-reduce variants measured
// neutral-to-worse; this latency-hidden form is fine at 512 blocks. Keep.
__global__ void build_table_kernel(const float* __restrict__ emb,
                                   const float* __restrict__ W,
                                   const float* __restrict__ bias,
                                   float* __restrict__ T) {
    const int kt = blockIdx.x;        // k*128 + t
    const int k  = kt >> 7;
    const int t  = kt & 127;
    const int v  = threadIdx.x;       // 0..127

    __shared__ float4 e[Dn / 4];
    if (threadIdx.x < Dn / 4) {
        e[threadIdx.x] = ((const float4*)(emb + t * Dn))[threadIdx.x];
    }
    __syncthreads();

    const float4* w = (const float4*)(W + (size_t)v * (Dn * N1) + k * Dn);
    float acc = (k == 0) ? bias[v] : 0.f;  // fold bias into slot-0 table
#pragma unroll
    for (int i = 0; i < Dn / 4; ++i) {
        float4 wv = w[i];
        float4 ev = e[i];
        acc += wv.x * ev.x + wv.y * ev.y + wv.z * ev.z + wv.w * ev.w;
    }
    // quarter-major layout: q = v>>5, vlo = v&31; wave writes 128 B lines
    T[(size_t)(((v >> 5) * N1 + k) * Vn + t) * 32 + (v & 31)] = acc;
}

// Kernel B (R9): out[b,j,v] = sum_k T'[k][x[b,j-4+k]][v], bias folded into T'[0].
// Each block owns one v-quarter (32 floats) x 1024 consecutive positions; its
// 64 KiB slice of T is staged in LDS.
//
// R8 post-mortem: the un-swizzled stride-32-float rows are NOT conflict-free.
// For one ds_read_b128, the 8 lanes sharing vq (different gl, different random
// token rows) all hit byte slot vq*16 of their row -> same bank group regardless
// of row => 4-8-way serialization (the guide's documented attn case, G4).
// R9 fix: XOR-swizzle the float4 column by the row, idx4 = r*8 + (vq ^ (r&7)),
// applied identically on stage-write and gather-read (both-sides involution).
// Same-vq lanes now spread across bank groups by token low bits.
// Wave stores unchanged: 8 x 128 B full L2 lines. 64 KiB x 2 blocks/CU, 16 waves.
constexpr int ROWS = N1 * Vn;  // 512 table rows

__global__ void __launch_bounds__(512, 4)
ngram_logits_kernel(const int* __restrict__ x,
                    const float* __restrict__ T,
                    const float* __restrict__ bias,
                    float* __restrict__ out) {
    __shared__ float lds[ROWS * 32];  // 65536 B exactly

    const int q  = blockIdx.x & 3;   // v-quarter
    const int pb = blockIdx.x >> 2;  // position block, 0..127 (1024 positions each)

    // Stage this quarter of T: 512 rows x 32 floats = 4096 float4, coalesced
    // global reads; LDS writes column-swizzled by row (c ^= r&7).
    {
        const float4* src = (const float4*)(T + (size_t)q * (ROWS * 32));
        float4*       dst = (float4*)lds;
#pragma unroll
        for (int it = 0; it < 8; ++it) {
            const int f = it * 512 + threadIdx.x;  // linear float4 index
            const int r = f >> 3;                  // table row 0..511
            const int c = f & 7;                   // float4 column 0..7
            dst[r * 8 + (c ^ (r & 7))] = src[f];
        }
    }
    __syncthreads();

    const int vq = threadIdx.x & 7;   // float4 within the 32-float quarter
    const int gl = threadIdx.x >> 3;  // position group 0..63 within iteration
    const vfloat4* lv   = (const vfloat4*)lds;
    vfloat4*       outq = (vfloat4*)out;

#pragma unroll
    for (int it = 0; it < 4; ++it) {
        const int basepos = pb * 1024 + it * 256 + gl * 4;  // 4-aligned
        vfloat4*  ob      = outq + (size_t)basepos * 32 + q * 8 + vq;

        if ((basepos & (Ln - 1)) == 0) {
            // positions j=0..3 of a batch row: bias-only
            const vfloat4 bv = ((const vfloat4*)bias)[q * 8 + vq];
#pragma unroll
            for (int i = 0; i < 4; ++i)
                __builtin_nontemporal_store(bv, ob + i * 32);
            continue;
        }

        // token window w[0..6] = x[basepos-4 .. basepos+2]; both int4 loads aligned
        const int4 xa = *(const int4*)(x + basepos - 4);
        const int4 xb = *(const int4*)(x + basepos);
        const int  w[7] = {xa.x, xa.y, xa.z, xa.w, xb.x, xb.y, xb.z};

#pragma unroll
        for (int i = 0; i < 4; ++i) {
            // row r = k*128 + tok; swizzled float4 index = r*8 + (vq ^ (tok&7))
            // ((k*128+tok)&7 == tok&7)
            vfloat4 a = lv[(w[i] << 3) + (vq ^ (w[i] & 7))];
#pragma unroll
            for (int k = 1; k < N1; ++k) {
                const int tok = w[i + k];
                a += lv[((k * Vn + tok) << 3) + (vq ^ (tok & 7))];
            }
            __builtin_nontemporal_store(a, ob + i * 32);  // R6: nt stores required
        }
    }
}

extern "C" void kernel_launch(void* const* d_in, const int* in_sizes, int n_in,
                              void* d_out, int out_size, void* d_ws, size_t ws_size,
                              hipStream_t stream) {
    const int*   x    = (const int*)d_in[0];    // (B, L) int32
    const float* emb  = (const float*)d_in[1];  // (V, D) fp32
    const float* W    = (const float*)d_in[2];  // (V, D*(N-1)) fp32
    const float* bias = (const float*)d_in[3];  // (V,) fp32
    float*       out  = (float*)d_out;          // (B, L, V) fp32
    float*       T    = (float*)d_ws;           // (4, 4, 128, 32) fp32 = 256 KiB

    build_table_kernel<<<N1 * Vn, Vn, 0, stream>>>(emb, W, bias, T);

    // 4 v-quarters x 128 position-blocks = 512 blocks of 512 threads
    ngram_logits_kernel<<<512, 512, 0, stream>>>(x, T, bias, out);
}